// Round 1
// baseline (1372.017 us; speedup 1.0000x reference)
//
#include <hip/hip_runtime.h>
#include <hip/hip_bf16.h>

// EncoderLayer: B=4 S=1024 D=1024 H=16 DH=64 DFF=2048
// Round 1: correct fp32 baseline.
//   ws layout (floats):
//     q   [H][B*S][64]   at ofs 0        (4M floats)
//     k   [H][B*S][64]   at ofs 4M
//     v   [H][B*S][64]   at ofs 8M
//     h1  [B*S][D]       at ofs 12M      (attention output, heads concatenated)
//     ff  [B*S][DFF]     at ofs 16M      (8M floats)
//   total 24M floats = 96 MB ws.

constexpr int Bb  = 4;
constexpr int Ss  = 1024;
constexpr int Dd  = 1024;
constexpr int Hh  = 16;
constexpr int DH  = 64;
constexpr int DFF = 2048;
constexpr int MROWS = Bb * Ss;   // 4096

// ---------------------------------------------------------------------------
// Generic fp32 tiled GEMM: C[M,N] = A[M,K] @ B[K,N] (+bias, optional relu)
// 64x64 tile per 256-thread block, BK=16, each thread 4x4 outputs.
// ---------------------------------------------------------------------------
__device__ __forceinline__ void gemm_tile_f32(
    const float* __restrict__ A, int lda,
    const float* __restrict__ B, int ldb,
    const float* __restrict__ bias,
    float* __restrict__ C, int ldc,
    int K, int m0, int n0, bool relu)
{
  __shared__ float As[16][64];   // [kk][m]
  __shared__ float Bs[16][64];   // [kk][n]
  const int tid = threadIdx.x;       // 0..255
  const int tx  = tid & 15;          // n group
  const int ty  = tid >> 4;          // m group
  const int arow = tid >> 2;         // 0..63
  const int akk  = (tid & 3) * 4;    // 0,4,8,12
  const int brow = tid >> 4;         // 0..15
  const int bcol = (tid & 15) * 4;   // 0..60

  float acc[4][4];
  #pragma unroll
  for (int i = 0; i < 4; ++i)
    #pragma unroll
    for (int j = 0; j < 4; ++j) acc[i][j] = 0.f;

  for (int k0 = 0; k0 < K; k0 += 16) {
    __syncthreads();
    const float4 av = *(const float4*)(A + (size_t)(m0 + arow) * lda + k0 + akk);
    As[akk + 0][arow] = av.x;
    As[akk + 1][arow] = av.y;
    As[akk + 2][arow] = av.z;
    As[akk + 3][arow] = av.w;
    const float4 bv = *(const float4*)(B + (size_t)(k0 + brow) * ldb + n0 + bcol);
    *(float4*)&Bs[brow][bcol] = bv;
    __syncthreads();
    #pragma unroll
    for (int kk = 0; kk < 16; ++kk) {
      float a[4], b[4];
      *(float4*)a = *(const float4*)&As[kk][ty * 4];
      *(float4*)b = *(const float4*)&Bs[kk][tx * 4];
      #pragma unroll
      for (int i = 0; i < 4; ++i)
        #pragma unroll
        for (int j = 0; j < 4; ++j)
          acc[i][j] = fmaf(a[i], b[j], acc[i][j]);
    }
  }

  #pragma unroll
  for (int i = 0; i < 4; ++i) {
    const int row = m0 + ty * 4 + i;
    #pragma unroll
    for (int j = 0; j < 4; ++j) {
      const int col = n0 + tx * 4 + j;
      float v = acc[i][j];
      if (bias) v += bias[col];
      if (relu) v = fmaxf(v, 0.f);
      C[(size_t)row * ldc + col] = v;
    }
  }
}

// FFN GEMM wrapper: grid = (N/64, M/64)
__global__ __launch_bounds__(256) void ffn_gemm(
    const float* __restrict__ A, const float* __restrict__ B,
    const float* __restrict__ bias, float* __restrict__ C,
    int K, int N, int relu)
{
  const int n0 = blockIdx.x * 64;
  const int m0 = blockIdx.y * 64;
  gemm_tile_f32(A, K, B, N, bias, C, N, K, m0, n0, relu != 0);
}

// QKV projection: grid = (M/64, H, 3); out layout [H][B*S][64]
__global__ __launch_bounds__(256) void qkv_gemm(
    const float* __restrict__ x,
    const float* __restrict__ Wq, const float* __restrict__ Wk,
    const float* __restrict__ Wv,
    float* __restrict__ qb, float* __restrict__ kb, float* __restrict__ vb)
{
  const int m0    = blockIdx.x * 64;
  const int h     = blockIdx.y;
  const int which = blockIdx.z;
  const float* W = (which == 0) ? Wq : (which == 1) ? Wk : Wv;
  float* out     = (which == 0) ? qb : (which == 1) ? kb : vb;
  gemm_tile_f32(x, Dd,
                W + (size_t)h * Dd * DH, DH,
                nullptr,
                out + (size_t)h * MROWS * DH, DH,
                Dd, m0, 0, false);
}

// ---------------------------------------------------------------------------
// Flash-style attention, fp32. One 64-thread block = 64 q-rows of one (h,b).
// grid = (S/64, H*B). Each lane owns one q-row: q-row + acc in registers,
// K/V tiles staged in LDS (all compute reads are LDS broadcasts).
// Writes concatenated-heads output h1[B*S][D].
// ---------------------------------------------------------------------------
__global__ __launch_bounds__(64) void attn_kernel(
    const float* __restrict__ qb, const float* __restrict__ kb,
    const float* __restrict__ vb, float* __restrict__ h1)
{
  const int qt   = blockIdx.x;        // q tile 0..15
  const int h    = blockIdx.y >> 2;   // 0..15
  const int b    = blockIdx.y & 3;    // 0..3
  const int lane = threadIdx.x;       // 0..63

  const size_t base = ((size_t)h * Bb + b) * Ss * 64;
  const float* Q = qb + base + (size_t)qt * 64 * 64;
  const float* K = kb + base;
  const float* V = vb + base;

  float qreg[64];
  #pragma unroll
  for (int e = 0; e < 64; ++e) qreg[e] = Q[lane * 64 + e] * 0.125f; // fold 1/sqrt(64)
  float acc[64];
  #pragma unroll
  for (int e = 0; e < 64; ++e) acc[e] = 0.f;
  float m = -3.4e38f, l = 0.f;

  __shared__ float Ks[64][64];
  __shared__ float Vs[64][64];

  for (int kt = 0; kt < Ss / 64; ++kt) {
    __syncthreads();
    #pragma unroll 4
    for (int r = 0; r < 64; ++r) {
      Ks[r][lane] = K[(size_t)(kt * 64 + r) * 64 + lane];
      Vs[r][lane] = V[(size_t)(kt * 64 + r) * 64 + lane];
    }
    __syncthreads();

    #pragma unroll 1
    for (int c = 0; c < 4; ++c) {          // 4 chunks of 16 keys
      float s[16];
      float cmax = -3.4e38f;
      #pragma unroll
      for (int j = 0; j < 16; ++j) {
        const int kj = c * 16 + j;
        float s0 = 0.f, s1 = 0.f, s2 = 0.f, s3 = 0.f;
        #pragma unroll
        for (int e = 0; e < 64; e += 4) {
          s0 = fmaf(qreg[e + 0], Ks[kj][e + 0], s0);
          s1 = fmaf(qreg[e + 1], Ks[kj][e + 1], s1);
          s2 = fmaf(qreg[e + 2], Ks[kj][e + 2], s2);
          s3 = fmaf(qreg[e + 3], Ks[kj][e + 3], s3);
        }
        s[j] = (s0 + s1) + (s2 + s3);
        cmax = fmaxf(cmax, s[j]);
      }
      const float mnew  = fmaxf(m, cmax);
      const float scale = __expf(m - mnew);  // 0 on first chunk
      float psum = 0.f;
      float p[16];
      #pragma unroll
      for (int j = 0; j < 16; ++j) { p[j] = __expf(s[j] - mnew); psum += p[j]; }
      l = l * scale + psum;
      m = mnew;
      #pragma unroll
      for (int e = 0; e < 64; ++e) acc[e] *= scale;
      #pragma unroll
      for (int j = 0; j < 16; ++j) {
        const int kj = c * 16 + j;
        #pragma unroll
        for (int e = 0; e < 64; ++e)
          acc[e] = fmaf(p[j], Vs[kj][e], acc[e]);
      }
    }
  }

  const float inv = 1.f / l;
  const int row = b * Ss + qt * 64 + lane;        // row in [B*S]
  float* outp = h1 + (size_t)row * Dd + h * 64;
  #pragma unroll
  for (int e = 0; e < 64; ++e) outp[e] = acc[e] * inv;
}

// ---------------------------------------------------------------------------
extern "C" void kernel_launch(void* const* d_in, const int* in_sizes, int n_in,
                              void* d_out, int out_size, void* d_ws, size_t ws_size,
                              hipStream_t stream)
{
  const float* x  = (const float*)d_in[0];
  const float* Wq = (const float*)d_in[1];
  const float* Wk = (const float*)d_in[2];
  const float* Wv = (const float*)d_in[3];
  const float* W1 = (const float*)d_in[4];
  const float* b1 = (const float*)d_in[5];
  const float* W2 = (const float*)d_in[6];
  const float* b2 = (const float*)d_in[7];
  float* out = (float*)d_out;

  float* ws = (float*)d_ws;
  float* qb = ws;                          // 4M floats
  float* kb = ws + (size_t)4 * 1024 * 1024;
  float* vb = ws + (size_t)8 * 1024 * 1024;
  float* h1 = ws + (size_t)12 * 1024 * 1024;
  float* ff = ws + (size_t)16 * 1024 * 1024;

  // 1) QKV projections: [4096,1024] @ [1024,64] per head, 3 ways
  {
    dim3 grid(MROWS / 64, Hh, 3);
    qkv_gemm<<<grid, 256, 0, stream>>>(x, Wq, Wk, Wv, qb, kb, vb);
  }
  // 2) attention -> h1 [4096,1024]
  {
    dim3 grid(Ss / 64, Hh * Bb);
    attn_kernel<<<grid, 64, 0, stream>>>(qb, kb, vb, h1);
  }
  // 3) FFN1: relu(h1 @ W1 + b1) -> ff [4096,2048]
  {
    dim3 grid(DFF / 64, MROWS / 64);
    ffn_gemm<<<grid, 256, 0, stream>>>(h1, W1, b1, ff, Dd, DFF, 1);
  }
  // 4) FFN2: ff @ W2 + b2 -> out [4096,1024]
  {
    dim3 grid(Dd / 64, MROWS / 64);
    ffn_gemm<<<grid, 256, 0, stream>>>(ff, W2, b2, out, DFF, Dd, 0);
  }
}

// Round 2
// 768.763 us; speedup vs baseline: 1.7847x; 1.7847x over previous
//
#include <hip/hip_runtime.h>
#include <hip/hip_bf16.h>

// EncoderLayer: B=4 S=1024 D=1024 H=16 DH=64 DFF=2048
// Round 2: bf16 MFMA GEMMs (m97-style 128x128 tile, global_load_lds staging)
//          + 4-wave shared-staging fp32 flash attention.
//
// ws layout (bytes, 1 MB = 1<<20):
//   qkvf fp32 [3][H][B*S][64]          @ 0      (48 MB)
//   Xb   bf16 [4096][1024]             @ 48 MB  (8 MB)
//   Wqkvt bf16 [3072][1024]  (B^T)     @ 56 MB  (6 MB)
//   W1t  bf16 [2048][1024]   (B^T)     @ 62 MB  (4 MB)
//   W2t  bf16 [1024][2048]   (B^T)     @ 66 MB  (4 MB)
//   h1b  bf16 [4096][1024]             @ 70 MB  (8 MB)
//   ffb  bf16 [4096][2048]             @ 78 MB  (16 MB)  -> total 94 MB

typedef unsigned short u16;
typedef __attribute__((ext_vector_type(8))) short bfrag8;   // 8 bf16 = 4 VGPRs
typedef __attribute__((ext_vector_type(4))) float f32x4;

constexpr int Bb = 4, Ss = 1024, Dd = 1024, Hh = 16, DFF = 2048;
constexpr int MROWS = 4096;

__device__ __forceinline__ u16 f2bf(float f) {
  unsigned u = __float_as_uint(f);
  return (u16)((u + 0x7fffu + ((u >> 16) & 1u)) >> 16);
}

__device__ __forceinline__ void gload16(const void* g, void* l) {
  __builtin_amdgcn_global_load_lds(
      (const __attribute__((address_space(1))) unsigned int*)g,
      (__attribute__((address_space(3))) unsigned int*)l, 16, 0, 0);
}

// ---------------------------------------------------------------------------
// cvt fp32 -> bf16, 1 float4 per thread
// ---------------------------------------------------------------------------
__global__ __launch_bounds__(256) void cvt_bf16(const float* __restrict__ in,
                                                u16* __restrict__ out, int n4) {
  int i = blockIdx.x * 256 + threadIdx.x;
  if (i >= n4) return;
  float4 v = ((const float4*)in)[i];
  ushort4 o = make_ushort4(f2bf(v.x), f2bf(v.y), f2bf(v.z), f2bf(v.w));
  *(ushort4*)(out + (size_t)i * 4) = o;
}

// ---------------------------------------------------------------------------
// 64x64 tiled transpose + cvt: in[R][C] fp32 -> out[C][R] bf16
// ---------------------------------------------------------------------------
__device__ __forceinline__ void transpose64(const float* __restrict__ in,
                                            u16* __restrict__ out,
                                            int R, int C, int r0, int c0) {
  __shared__ float tile[64][65];
  const int t = threadIdx.x, cl = t & 63, rq = t >> 6;
#pragma unroll
  for (int i = 0; i < 16; ++i) {
    int rl = rq * 16 + i;
    tile[rl][cl] = in[(size_t)(r0 + rl) * C + c0 + cl];
  }
  __syncthreads();
#pragma unroll
  for (int i = 0; i < 16; ++i) {
    int oc = rq * 16 + i;
    out[(size_t)(c0 + oc) * R + r0 + cl] = f2bf(tile[cl][oc]);
  }
}

__global__ __launch_bounds__(256) void transpose_cvt(const float* __restrict__ in,
                                                     u16* __restrict__ out,
                                                     int R, int C) {
  transpose64(in, out, R, C, blockIdx.x * 64, blockIdx.y * 64);
}

// Wq/Wk/Wv [16][1024][64] -> Wqkvt [3072][1024]; grid (16, 48)
__global__ __launch_bounds__(256) void qkv_transpose_cvt(
    const float* __restrict__ Wq, const float* __restrict__ Wk,
    const float* __restrict__ Wv, u16* __restrict__ out) {
  const int z = blockIdx.y;            // 0..47
  const int which = z >> 4, h = z & 15;
  const float* in = (which == 0 ? Wq : which == 1 ? Wk : Wv) + (size_t)h * 1024 * 64;
  u16* o = out + (size_t)z * 64 * 1024;        // rows z*64 .. z*64+63 of [3072][1024]
  transpose64(in, o, 1024, 64, blockIdx.x * 64, 0);
}

// ---------------------------------------------------------------------------
// bf16 MFMA GEMM, 128x128 tile, BK=32, 4 waves, each wave 64x64 (4x4 frags).
// A [M=4096][K] bf16 row-major, Bt [N][K] bf16 row-major (= B^T).
// EPI 0: scatter fp32 into qkv buffers; 1: +bias,relu -> bf16 C[M][N];
// EPI 2: +bias -> fp32 C[M][N].
// ---------------------------------------------------------------------------
template <int EPI>
__global__ __launch_bounds__(256) void mfma_gemm(
    const u16* __restrict__ A, const u16* __restrict__ Bt,
    const float* __restrict__ bias, void* __restrict__ Cout, int N, int K) {
  __shared__ alignas(16) u16 Asm[128 * 32];   // [row][k] row stride 64 B
  __shared__ alignas(16) u16 Bsm[128 * 32];
  const int tid = threadIdx.x;
  const int wid = tid >> 6, lane = tid & 63;
  const int m0 = blockIdx.y * 128, n0 = blockIdx.x * 128;
  const int wr = wid >> 1, wc = wid & 1;       // wave's 64x64 quadrant
  const int fr = lane & 15, krow = lane >> 4;  // fragment row, k-group

  // staging: 256 thr x 16 B covers half a tile; two passes per tile
  const int srow = tid >> 2;                   // 0..63
  const int sk = (tid & 3) * 8;                // k element 0,8,16,24
  const u16* ga0 = A + (size_t)(m0 + srow) * K + sk;
  const u16* ga1 = A + (size_t)(m0 + srow + 64) * K + sk;
  const u16* gb0 = Bt + (size_t)(n0 + srow) * K + sk;
  const u16* gb1 = Bt + (size_t)(n0 + srow + 64) * K + sk;
  char* lA0 = (char*)Asm + tid * 16;
  char* lA1 = lA0 + 4096;
  char* lB0 = (char*)Bsm + tid * 16;
  char* lB1 = lB0 + 4096;

  f32x4 acc[4][4];
#pragma unroll
  for (int i = 0; i < 4; ++i)
#pragma unroll
    for (int j = 0; j < 4; ++j) acc[i][j] = (f32x4){0.f, 0.f, 0.f, 0.f};

  const char* pa = (const char*)Asm + (wr * 64 + fr) * 64 + krow * 16;
  const char* pb = (const char*)Bsm + (wc * 64 + fr) * 64 + krow * 16;

  for (int kt = 0; kt < K / 32; ++kt) {
    __syncthreads();                 // previous tile fully consumed
    gload16(ga0 + kt * 32, lA0);
    gload16(ga1 + kt * 32, lA1);
    gload16(gb0 + kt * 32, lB0);
    gload16(gb1 + kt * 32, lB1);
    __syncthreads();                 // vmcnt(0) drained by compiler before barrier

    bfrag8 af[4], bfv[4];
#pragma unroll
    for (int i = 0; i < 4; ++i) af[i] = *(const bfrag8*)(pa + i * 1024);
#pragma unroll
    for (int j = 0; j < 4; ++j) bfv[j] = *(const bfrag8*)(pb + j * 1024);
#pragma unroll
    for (int i = 0; i < 4; ++i)
#pragma unroll
      for (int j = 0; j < 4; ++j)
        acc[i][j] = __builtin_amdgcn_mfma_f32_16x16x32_bf16(af[i], bfv[j], acc[i][j], 0, 0, 0);
  }

  // epilogue: C/D map col=lane&15, row=(lane>>4)*4+reg  [verified m89/m91]
  const int orow = (lane >> 4) * 4;
  const int ocol = lane & 15;
#pragma unroll
  for (int i = 0; i < 4; ++i) {
#pragma unroll
    for (int j = 0; j < 4; ++j) {
      const int gn = n0 + wc * 64 + j * 16 + ocol;
#pragma unroll
      for (int r = 0; r < 4; ++r) {
        const int gm = m0 + wr * 64 + i * 16 + orow + r;
        float v = acc[i][j][r];
        if (EPI == 0) {
          const int which = gn >> 10, h = (gn >> 6) & 15, e = gn & 63;
          ((float*)Cout)[(size_t)which * 4194304 + (size_t)h * 262144 +
                         (size_t)gm * 64 + e] = v;
        } else if (EPI == 1) {
          v = fmaxf(v + bias[gn], 0.f);
          ((u16*)Cout)[(size_t)gm * N + gn] = f2bf(v);
        } else {
          ((float*)Cout)[(size_t)gm * N + gn] = v + bias[gn];
        }
      }
    }
  }
}

// ---------------------------------------------------------------------------
// fp32 flash attention: 256-thread block = 4 waves sharing K/V LDS tiles.
// Wave w handles q-rows [blockIdx.x*256 + w*64, +64); one lane = one q-row.
// grid = (S/256, H*B). Output: h1b bf16 [B*S][1024] heads concatenated.
// ---------------------------------------------------------------------------
__global__ __launch_bounds__(256) void attn_kernel(
    const float* __restrict__ qb, const float* __restrict__ kb,
    const float* __restrict__ vb, u16* __restrict__ h1) {
  const int wid = threadIdx.x >> 6, lane = threadIdx.x & 63;
  const int h = blockIdx.y >> 2, b = blockIdx.y & 3;
  const size_t base = ((size_t)h * Bb + b) * Ss * 64;
  const int qrow = blockIdx.x * 256 + wid * 64 + lane;   // 0..1023 within S

  const float* Q = qb + base + (size_t)qrow * 64;
  const float* K = kb + base;
  const float* V = vb + base;

  float qreg[64];
#pragma unroll
  for (int e4 = 0; e4 < 16; ++e4) {
    float4 qv = ((const float4*)Q)[e4];
    qreg[e4 * 4 + 0] = qv.x * 0.125f;   // fold 1/sqrt(64)
    qreg[e4 * 4 + 1] = qv.y * 0.125f;
    qreg[e4 * 4 + 2] = qv.z * 0.125f;
    qreg[e4 * 4 + 3] = qv.w * 0.125f;
  }
  float acc[64];
#pragma unroll
  for (int e = 0; e < 64; ++e) acc[e] = 0.f;
  float m = -3.4e38f, l = 0.f;

  __shared__ float Ks[64][64];
  __shared__ float Vs[64][64];
  const int srow = threadIdx.x >> 2;          // 0..63
  const int scol = (threadIdx.x & 3) * 16;    // 0,16,32,48

  for (int kt = 0; kt < Ss / 64; ++kt) {
    __syncthreads();
    {
      const float4* Kg = (const float4*)(K + (size_t)(kt * 64 + srow) * 64 + scol);
      const float4* Vg = (const float4*)(V + (size_t)(kt * 64 + srow) * 64 + scol);
#pragma unroll
      for (int i = 0; i < 4; ++i) *(float4*)&Ks[srow][scol + i * 4] = Kg[i];
#pragma unroll
      for (int i = 0; i < 4; ++i) *(float4*)&Vs[srow][scol + i * 4] = Vg[i];
    }
    __syncthreads();

#pragma unroll 1
    for (int c = 0; c < 4; ++c) {            // 4 chunks of 16 keys
      float s[16];
      float cmax = -3.4e38f;
#pragma unroll
      for (int j = 0; j < 16; ++j) {
        const int kj = c * 16 + j;
        float s0 = 0.f, s1 = 0.f, s2 = 0.f, s3 = 0.f;
#pragma unroll
        for (int e = 0; e < 64; e += 4) {
          s0 = fmaf(qreg[e + 0], Ks[kj][e + 0], s0);
          s1 = fmaf(qreg[e + 1], Ks[kj][e + 1], s1);
          s2 = fmaf(qreg[e + 2], Ks[kj][e + 2], s2);
          s3 = fmaf(qreg[e + 3], Ks[kj][e + 3], s3);
        }
        s[j] = (s0 + s1) + (s2 + s3);
        cmax = fmaxf(cmax, s[j]);
      }
      const float mnew = fmaxf(m, cmax);
      const float scale = __expf(m - mnew);
      float psum = 0.f;
      float p[16];
#pragma unroll
      for (int j = 0; j < 16; ++j) { p[j] = __expf(s[j] - mnew); psum += p[j]; }
      l = l * scale + psum;
      m = mnew;
#pragma unroll
      for (int e = 0; e < 64; ++e) acc[e] *= scale;
#pragma unroll
      for (int j = 0; j < 16; ++j) {
        const int kj = c * 16 + j;
#pragma unroll
        for (int e = 0; e < 64; ++e) acc[e] = fmaf(p[j], Vs[kj][e], acc[e]);
      }
    }
  }

  const float inv = 1.f / l;
  u16* op = h1 + (size_t)(b * Ss + qrow) * Dd + h * 64;
#pragma unroll
  for (int e4 = 0; e4 < 16; ++e4) {
    ushort4 o = make_ushort4(f2bf(acc[e4 * 4 + 0] * inv), f2bf(acc[e4 * 4 + 1] * inv),
                             f2bf(acc[e4 * 4 + 2] * inv), f2bf(acc[e4 * 4 + 3] * inv));
    *(ushort4*)(op + e4 * 4) = o;
  }
}

// ---------------------------------------------------------------------------
extern "C" void kernel_launch(void* const* d_in, const int* in_sizes, int n_in,
                              void* d_out, int out_size, void* d_ws, size_t ws_size,
                              hipStream_t stream) {
  const float* x  = (const float*)d_in[0];
  const float* Wq = (const float*)d_in[1];
  const float* Wk = (const float*)d_in[2];
  const float* Wv = (const float*)d_in[3];
  const float* W1 = (const float*)d_in[4];
  const float* b1 = (const float*)d_in[5];
  const float* W2 = (const float*)d_in[6];
  const float* b2 = (const float*)d_in[7];

  const size_t MB = 1u << 20;
  char* w = (char*)d_ws;
  float* qkvf = (float*)w;                 // 48 MB: q|k|v each [16][4096][64]
  u16* Xb    = (u16*)(w + 48 * MB);
  u16* Wqkvt = (u16*)(w + 56 * MB);
  u16* W1t   = (u16*)(w + 62 * MB);
  u16* W2t   = (u16*)(w + 66 * MB);
  u16* h1b   = (u16*)(w + 70 * MB);
  u16* ffb   = (u16*)(w + 78 * MB);

  // input conversions / weight repacks
  cvt_bf16<<<4096, 256, 0, stream>>>(x, Xb, 1048576);
  qkv_transpose_cvt<<<dim3(16, 48), 256, 0, stream>>>(Wq, Wk, Wv, Wqkvt);
  transpose_cvt<<<dim3(16, 32), 256, 0, stream>>>(W1, W1t, 1024, 2048);
  transpose_cvt<<<dim3(32, 16), 256, 0, stream>>>(W2, W2t, 2048, 1024);

  // QKV: [4096,1024] @ [1024,3072] -> scatter fp32 q/k/v
  mfma_gemm<0><<<dim3(24, 32), 256, 0, stream>>>(Xb, Wqkvt, nullptr, qkvf, 3072, 1024);
  // attention -> h1b bf16 [4096][1024]
  attn_kernel<<<dim3(4, 64), 256, 0, stream>>>(qkvf, qkvf + 4194304, qkvf + 8388608, h1b);
  // FFN1: relu(h1 @ W1 + b1) -> ffb bf16 [4096][2048]
  mfma_gemm<1><<<dim3(16, 32), 256, 0, stream>>>(h1b, W1t, b1, ffb, 2048, 1024);
  // FFN2: ff @ W2 + b2 -> out fp32 [4096][1024]
  mfma_gemm<2><<<dim3(8, 32), 256, 0, stream>>>(ffb, W2t, b2, d_out, 1024, 2048);
}

// Round 3
// 277.607 us; speedup vs baseline: 4.9423x; 2.7693x over previous
//
#include <hip/hip_runtime.h>
#include <hip/hip_bf16.h>

// EncoderLayer: B=4 S=1024 D=1024 H=16 DH=64 DFF=2048
// Round 3: MFMA flash attention (bf16 q/k/vT from QKV GEMM epilogue),
//          T2 XOR-swizzled LDS tiles, online softmax via 16-lane shfl reduce.
//
// ws layout (bytes):
//   qkvb bf16: q[64hb][1024][64] | k[...] | vT[64hb][64][1024]  @ 0   (24 MB)
//   Xb    bf16 [4096][1024]             @ 24 MB (8 MB)
//   Wqkvt bf16 [3072][1024]  (B^T)      @ 32 MB (6 MB)
//   W1t   bf16 [2048][1024]  (B^T)      @ 38 MB (4 MB)
//   W2t   bf16 [1024][2048]  (B^T)      @ 42 MB (4 MB)
//   h1b   bf16 [4096][1024]             @ 46 MB (8 MB)
//   ffb   bf16 [4096][2048]             @ 54 MB (16 MB)  -> 70 MB total

typedef unsigned short u16;
typedef __attribute__((ext_vector_type(8))) short bfrag8;   // 8 bf16 = 4 VGPRs
typedef __attribute__((ext_vector_type(4))) float f32x4;

constexpr int Bb = 4, Ss = 1024, Dd = 1024, Hh = 16, DFF = 2048;

__device__ __forceinline__ u16 f2bf(float f) {
  unsigned u = __float_as_uint(f);
  return (u16)((u + 0x7fffu + ((u >> 16) & 1u)) >> 16);
}

// T2 XOR swizzle for 128-byte-row LDS tiles: spread rows across 16B slots.
__device__ __forceinline__ int swz(int byte) {
  return byte ^ (((byte >> 7) & 7) << 4);
}

__device__ __forceinline__ void gload16(const void* g, void* l) {
  __builtin_amdgcn_global_load_lds(
      (const __attribute__((address_space(1))) unsigned int*)g,
      (__attribute__((address_space(3))) unsigned int*)l, 16, 0, 0);
}

// ---------------------------------------------------------------------------
__global__ __launch_bounds__(256) void cvt_bf16(const float* __restrict__ in,
                                                u16* __restrict__ out, int n4) {
  int i = blockIdx.x * 256 + threadIdx.x;
  if (i >= n4) return;
  float4 v = ((const float4*)in)[i];
  ushort4 o = make_ushort4(f2bf(v.x), f2bf(v.y), f2bf(v.z), f2bf(v.w));
  *(ushort4*)(out + (size_t)i * 4) = o;
}

__device__ __forceinline__ void transpose64(const float* __restrict__ in,
                                            u16* __restrict__ out,
                                            int R, int C, int r0, int c0) {
  __shared__ float tile[64][65];
  const int t = threadIdx.x, cl = t & 63, rq = t >> 6;
#pragma unroll
  for (int i = 0; i < 16; ++i) {
    int rl = rq * 16 + i;
    tile[rl][cl] = in[(size_t)(r0 + rl) * C + c0 + cl];
  }
  __syncthreads();
#pragma unroll
  for (int i = 0; i < 16; ++i) {
    int oc = rq * 16 + i;
    out[(size_t)(c0 + oc) * R + r0 + cl] = f2bf(tile[cl][oc]);
  }
}

__global__ __launch_bounds__(256) void transpose_cvt(const float* __restrict__ in,
                                                     u16* __restrict__ out,
                                                     int R, int C) {
  transpose64(in, out, R, C, blockIdx.x * 64, blockIdx.y * 64);
}

__global__ __launch_bounds__(256) void qkv_transpose_cvt(
    const float* __restrict__ Wq, const float* __restrict__ Wk,
    const float* __restrict__ Wv, u16* __restrict__ out) {
  const int z = blockIdx.y;            // 0..47
  const int which = z >> 4, h = z & 15;
  const float* in = (which == 0 ? Wq : which == 1 ? Wk : Wv) + (size_t)h * 1024 * 64;
  u16* o = out + (size_t)z * 64 * 1024;
  transpose64(in, o, 1024, 64, blockIdx.x * 64, 0);
}

// ---------------------------------------------------------------------------
// bf16 MFMA GEMM, 128x128 tile, BK=32, 4 waves x (64x64).
// EPI 0: scatter bf16 q/k/vT; 1: +bias,relu -> bf16; 2: +bias -> fp32.
// ---------------------------------------------------------------------------
template <int EPI>
__global__ __launch_bounds__(256) void mfma_gemm(
    const u16* __restrict__ A, const u16* __restrict__ Bt,
    const float* __restrict__ bias, void* __restrict__ Cout, int N, int K) {
  __shared__ alignas(16) u16 Asm[128 * 32];   // [row][k], row stride 64 B
  __shared__ alignas(16) u16 Bsm[128 * 32];
  const int tid = threadIdx.x;
  const int wid = tid >> 6, lane = tid & 63;
  const int m0 = blockIdx.y * 128, n0 = blockIdx.x * 128;
  const int wr = wid >> 1, wc = wid & 1;
  const int fr = lane & 15, krow = lane >> 4;

  const int srow = tid >> 2;
  const int sk = (tid & 3) * 8;
  const u16* ga0 = A + (size_t)(m0 + srow) * K + sk;
  const u16* ga1 = A + (size_t)(m0 + srow + 64) * K + sk;
  const u16* gb0 = Bt + (size_t)(n0 + srow) * K + sk;
  const u16* gb1 = Bt + (size_t)(n0 + srow + 64) * K + sk;
  char* lA0 = (char*)Asm + tid * 16;
  char* lA1 = lA0 + 4096;
  char* lB0 = (char*)Bsm + tid * 16;
  char* lB1 = lB0 + 4096;

  f32x4 acc[4][4];
#pragma unroll
  for (int i = 0; i < 4; ++i)
#pragma unroll
    for (int j = 0; j < 4; ++j) acc[i][j] = (f32x4){0.f, 0.f, 0.f, 0.f};

  const char* pa = (const char*)Asm + (wr * 64 + fr) * 64 + krow * 16;
  const char* pb = (const char*)Bsm + (wc * 64 + fr) * 64 + krow * 16;

  for (int kt = 0; kt < K / 32; ++kt) {
    __syncthreads();
    gload16(ga0 + kt * 32, lA0);
    gload16(ga1 + kt * 32, lA1);
    gload16(gb0 + kt * 32, lB0);
    gload16(gb1 + kt * 32, lB1);
    __syncthreads();

    bfrag8 af[4], bfv[4];
#pragma unroll
    for (int i = 0; i < 4; ++i) af[i] = *(const bfrag8*)(pa + i * 1024);
#pragma unroll
    for (int j = 0; j < 4; ++j) bfv[j] = *(const bfrag8*)(pb + j * 1024);
#pragma unroll
    for (int i = 0; i < 4; ++i)
#pragma unroll
      for (int j = 0; j < 4; ++j)
        acc[i][j] = __builtin_amdgcn_mfma_f32_16x16x32_bf16(af[i], bfv[j], acc[i][j], 0, 0, 0);
  }

  const int orow = (lane >> 4) * 4;
  const int ocol = lane & 15;
#pragma unroll
  for (int i = 0; i < 4; ++i) {
#pragma unroll
    for (int j = 0; j < 4; ++j) {
      const int gn = n0 + wc * 64 + j * 16 + ocol;
      const int gm0 = m0 + wr * 64 + i * 16 + orow;
      if (EPI == 0) {
        // q/k: [hb][s][64]; vT: [hb][e][1024]
        const int which = gn >> 10, hh = (gn >> 6) & 15, e = gn & 63;
        const int bb = gm0 >> 10, s0 = gm0 & 1023;
        const int hb = hh * 4 + bb;
        u16* oq = (u16*)Cout;
        if (which < 2) {
#pragma unroll
          for (int r = 0; r < 4; ++r)
            oq[(size_t)which * 4194304 + ((size_t)hb * 1024 + s0 + r) * 64 + e] =
                f2bf(acc[i][j][r]);
        } else {
          ushort4 pk = make_ushort4(f2bf(acc[i][j][0]), f2bf(acc[i][j][1]),
                                    f2bf(acc[i][j][2]), f2bf(acc[i][j][3]));
          *(ushort4*)&oq[8388608 + ((size_t)hb * 64 + e) * 1024 + s0] = pk;
        }
      } else if (EPI == 1) {
#pragma unroll
        for (int r = 0; r < 4; ++r) {
          float v = fmaxf(acc[i][j][r] + bias[gn], 0.f);
          ((u16*)Cout)[(size_t)(gm0 + r) * N + gn] = f2bf(v);
        }
      } else {
#pragma unroll
        for (int r = 0; r < 4; ++r)
          ((float*)Cout)[(size_t)(gm0 + r) * N + gn] = acc[i][j][r] + bias[gn];
      }
    }
  }
}

// ---------------------------------------------------------------------------
// MFMA flash attention. Block = 128 q-rows of one (h,b); 4 waves x 32 rows.
// K tile [64k][64e], Vt tile [64e][64k] in XOR-swizzled LDS; P per-wave LDS.
// grid = (S/128, H*B).
// ---------------------------------------------------------------------------
__global__ __launch_bounds__(256) void attn_mfma(
    const u16* __restrict__ qb, const u16* __restrict__ kb,
    const u16* __restrict__ vtb, u16* __restrict__ h1) {
  __shared__ alignas(16) u16 Ks[64 * 64];
  __shared__ alignas(16) u16 Vs[64 * 64];       // transposed: [e][k]
  __shared__ alignas(16) u16 Ps[4][32 * 64];    // per-wave P [q][k]
  const int tid = threadIdx.x, wid = tid >> 6, lane = tid & 63;
  const int hb = blockIdx.y, h = hb >> 2, b = hb & 3;
  const int q0 = blockIdx.x * 128 + wid * 32;
  const int fr = lane & 15, hi = lane >> 4;

  const u16* Qg = qb + ((size_t)hb * 1024 + q0) * 64;
  const u16* Kg = kb + (size_t)hb * 1024 * 64;
  const u16* Vg = vtb + (size_t)hb * 64 * 1024;
  char* Kw = (char*)Ks;
  char* Vw = (char*)Vs;
  char* Pw = (char*)Ps[wid];

  // Q fragments: rows m*16+fr, k-slice kk*32 + hi*8
  bfrag8 qf[2][2];
#pragma unroll
  for (int m = 0; m < 2; ++m)
#pragma unroll
    for (int kk = 0; kk < 2; ++kk)
      qf[m][kk] = *(const bfrag8*)(Qg + (m * 16 + fr) * 64 + kk * 32 + hi * 8);

  f32x4 acc_o[2][4];
#pragma unroll
  for (int m = 0; m < 2; ++m)
#pragma unroll
    for (int en = 0; en < 4; ++en) acc_o[m][en] = (f32x4){0.f, 0.f, 0.f, 0.f};
  float mrun[2][4], lrun[2][4];
#pragma unroll
  for (int m = 0; m < 2; ++m)
#pragma unroll
    for (int r = 0; r < 4; ++r) { mrun[m][r] = -3.0e38f; lrun[m][r] = 0.f; }

  const int srow0 = tid >> 3;          // 0..31
  const int scol = (tid & 7) * 8;      // elem offset, 16B units

  for (int kt = 0; kt < 16; ++kt) {
    __syncthreads();
    // stage K + Vt (2 passes of 32 rows each), swizzled ds_write_b128
    bfrag8 kv0 = *(const bfrag8*)(Kg + (size_t)(kt * 64 + srow0) * 64 + scol);
    bfrag8 kv1 = *(const bfrag8*)(Kg + (size_t)(kt * 64 + srow0 + 32) * 64 + scol);
    bfrag8 vv0 = *(const bfrag8*)(Vg + (size_t)srow0 * 1024 + kt * 64 + scol);
    bfrag8 vv1 = *(const bfrag8*)(Vg + (size_t)(srow0 + 32) * 1024 + kt * 64 + scol);
    *(bfrag8*)(Kw + swz(srow0 * 128 + scol * 2)) = kv0;
    *(bfrag8*)(Kw + swz((srow0 + 32) * 128 + scol * 2)) = kv1;
    *(bfrag8*)(Vw + swz(srow0 * 128 + scol * 2)) = vv0;
    *(bfrag8*)(Vw + swz((srow0 + 32) * 128 + scol * 2)) = vv1;
    __syncthreads();

    // ---- QK^T: sc[m][kn] = Q(32x64) @ K^T(64x64) -> 32x64 scores
    f32x4 sc[2][4];
#pragma unroll
    for (int m = 0; m < 2; ++m)
#pragma unroll
      for (int kn = 0; kn < 4; ++kn) sc[m][kn] = (f32x4){0.f, 0.f, 0.f, 0.f};
    bfrag8 kf[4][2];
#pragma unroll
    for (int kn = 0; kn < 4; ++kn)
#pragma unroll
      for (int kk = 0; kk < 2; ++kk)
        kf[kn][kk] = *(const bfrag8*)(Kw + swz((kn * 16 + fr) * 128 + kk * 64 + hi * 16));
#pragma unroll
    for (int m = 0; m < 2; ++m)
#pragma unroll
      for (int kn = 0; kn < 4; ++kn)
#pragma unroll
        for (int kk = 0; kk < 2; ++kk)
          sc[m][kn] = __builtin_amdgcn_mfma_f32_16x16x32_bf16(qf[m][kk], kf[kn][kk],
                                                              sc[m][kn], 0, 0, 0);

    // ---- online softmax (rows spread: row = m*16 + hi*4 + r, col = kn*16 + fr)
#pragma unroll
    for (int m = 0; m < 2; ++m) {
      float ss[4][4];                 // [kn][r], scaled scores
#pragma unroll
      for (int kn = 0; kn < 4; ++kn)
#pragma unroll
        for (int r = 0; r < 4; ++r) ss[kn][r] = sc[m][kn][r] * 0.125f;
      float rmax[4];
#pragma unroll
      for (int r = 0; r < 4; ++r)
        rmax[r] = fmaxf(fmaxf(ss[0][r], ss[1][r]), fmaxf(ss[2][r], ss[3][r]));
#pragma unroll
      for (int mk = 1; mk <= 8; mk <<= 1)
#pragma unroll
        for (int r = 0; r < 4; ++r)
          rmax[r] = fmaxf(rmax[r], __shfl_xor(rmax[r], mk));
      float scl[4];
#pragma unroll
      for (int r = 0; r < 4; ++r) {
        const float mnew = fmaxf(mrun[m][r], rmax[r]);
        scl[r] = __expf(mrun[m][r] - mnew);
        mrun[m][r] = mnew;
      }
#pragma unroll
      for (int kn = 0; kn < 4; ++kn)
#pragma unroll
        for (int r = 0; r < 4; ++r) ss[kn][r] = __expf(ss[kn][r] - mrun[m][r]);
      float ps[4];
#pragma unroll
      for (int r = 0; r < 4; ++r)
        ps[r] = (ss[0][r] + ss[1][r]) + (ss[2][r] + ss[3][r]);
#pragma unroll
      for (int mk = 1; mk <= 8; mk <<= 1)
#pragma unroll
        for (int r = 0; r < 4; ++r) ps[r] += __shfl_xor(ps[r], mk);
#pragma unroll
      for (int r = 0; r < 4; ++r) lrun[m][r] = lrun[m][r] * scl[r] + ps[r];
#pragma unroll
      for (int en = 0; en < 4; ++en)
#pragma unroll
        for (int r = 0; r < 4; ++r) acc_o[m][en][r] *= scl[r];
      // write P as bf16 into per-wave swizzled LDS
#pragma unroll
      for (int kn = 0; kn < 4; ++kn)
#pragma unroll
        for (int r = 0; r < 4; ++r)
          *(u16*)(Pw + swz((m * 16 + hi * 4 + r) * 128 + (kn * 16 + fr) * 2)) =
              f2bf(ss[kn][r]);
    }

    // ---- PV: acc_o[m][en] += P(32x64) @ Vt^T  (Vt rows = e, cols = k)
    bfrag8 vf[4][2], pf[2][2];
#pragma unroll
    for (int en = 0; en < 4; ++en)
#pragma unroll
      for (int kf2 = 0; kf2 < 2; ++kf2)
        vf[en][kf2] = *(const bfrag8*)(Vw + swz((en * 16 + fr) * 128 + kf2 * 64 + hi * 16));
#pragma unroll
    for (int m = 0; m < 2; ++m)
#pragma unroll
      for (int kf2 = 0; kf2 < 2; ++kf2)
        pf[m][kf2] = *(const bfrag8*)(Pw + swz((m * 16 + fr) * 128 + kf2 * 64 + hi * 16));
#pragma unroll
    for (int m = 0; m < 2; ++m)
#pragma unroll
      for (int en = 0; en < 4; ++en)
#pragma unroll
        for (int kf2 = 0; kf2 < 2; ++kf2)
          acc_o[m][en] = __builtin_amdgcn_mfma_f32_16x16x32_bf16(pf[m][kf2], vf[en][kf2],
                                                                 acc_o[m][en], 0, 0, 0);
  }

  // epilogue: O = acc_o / l ; row = q0 + m*16 + hi*4 + r, col e = en*16 + fr
#pragma unroll
  for (int m = 0; m < 2; ++m) {
    float inv[4];
#pragma unroll
    for (int r = 0; r < 4; ++r) inv[r] = 1.f / lrun[m][r];
#pragma unroll
    for (int en = 0; en < 4; ++en)
#pragma unroll
      for (int r = 0; r < 4; ++r) {
        const int s = q0 + m * 16 + hi * 4 + r;
        h1[((size_t)(b * 1024 + s)) * 1024 + h * 64 + en * 16 + fr] =
            f2bf(acc_o[m][en][r] * inv[r]);
      }
  }
}

// ---------------------------------------------------------------------------
extern "C" void kernel_launch(void* const* d_in, const int* in_sizes, int n_in,
                              void* d_out, int out_size, void* d_ws, size_t ws_size,
                              hipStream_t stream) {
  const float* x  = (const float*)d_in[0];
  const float* Wq = (const float*)d_in[1];
  const float* Wk = (const float*)d_in[2];
  const float* Wv = (const float*)d_in[3];
  const float* W1 = (const float*)d_in[4];
  const float* b1 = (const float*)d_in[5];
  const float* W2 = (const float*)d_in[6];
  const float* b2 = (const float*)d_in[7];

  const size_t MB = 1u << 20;
  char* w = (char*)d_ws;
  u16* qkvb  = (u16*)w;                    // 24 MB: q | k | vT
  u16* Xb    = (u16*)(w + 24 * MB);
  u16* Wqkvt = (u16*)(w + 32 * MB);
  u16* W1t   = (u16*)(w + 38 * MB);
  u16* W2t   = (u16*)(w + 42 * MB);
  u16* h1b   = (u16*)(w + 46 * MB);
  u16* ffb   = (u16*)(w + 54 * MB);

  cvt_bf16<<<4096, 256, 0, stream>>>(x, Xb, 1048576);
  qkv_transpose_cvt<<<dim3(16, 48), 256, 0, stream>>>(Wq, Wk, Wv, Wqkvt);
  transpose_cvt<<<dim3(16, 32), 256, 0, stream>>>(W1, W1t, 1024, 2048);
  transpose_cvt<<<dim3(32, 16), 256, 0, stream>>>(W2, W2t, 2048, 1024);

  // QKV: [4096,1024] @ [1024,3072] -> bf16 q/k/vT scatter
  mfma_gemm<0><<<dim3(24, 32), 256, 0, stream>>>(Xb, Wqkvt, nullptr, qkvb, 3072, 1024);
  // attention -> h1b bf16 [4096][1024]
  attn_mfma<<<dim3(8, 64), 256, 0, stream>>>(qkvb, qkvb + 4194304, qkvb + 8388608, h1b);
  // FFN1: relu(h1 @ W1 + b1) -> ffb bf16 [4096][2048]
  mfma_gemm<1><<<dim3(16, 32), 256, 0, stream>>>(h1b, W1t, b1, ffb, 2048, 1024);
  // FFN2: ff @ W2 + b2 -> out fp32 [4096][1024]
  mfma_gemm<2><<<dim3(8, 32), 256, 0, stream>>>(ffb, W2t, b2, d_out, 1024, 2048);
}